// Round 3
// baseline (73.567 us; speedup 1.0000x reference)
//
#include <hip/hip_runtime.h>
#include <math.h>

#define BB 8
#define SS 512
#define DD 256
#define PP (SS * (SS - 1) / 2)                  // 130816 pairs per batch
#define STRIP 64
#define NSTRIP (SS / STRIP)                      // 8 strips per batch
#define SUPER_PER_B (NSTRIP * (NSTRIP + 1) / 2)  // 36 triangular 64x64 supertiles
#define NBLOCKS (BB * SUPER_PER_B)               // 288 blocks

typedef short bf16x8 __attribute__((ext_vector_type(8)));
typedef float f32x4 __attribute__((ext_vector_type(4)));

// fp32 -> bf16 round-to-nearest-even (finite gaussian inputs, no NaN path)
static __device__ inline unsigned short f2bf(float f) {
    unsigned int u = __float_as_uint(f);
    unsigned int r = u + 0x7fffu + ((u >> 16) & 1u);
    return (unsigned short)(r >> 16);
}

// Stage one 64-row panel: fp32 global -> bf16 LDS (16B-chunk XOR swizzle) + fp32 norms.
// f = it*256 + t: consecutive threads load consecutive float4 (fully coalesced);
// each iteration, all 64 lanes of a wave hold the SAME row -> wave-reduce the norm.
static __device__ inline void stage_panel(const float* __restrict__ src,
                                          unsigned short* panel, float* nrm,
                                          int t, int lane) {
    #pragma unroll
    for (int it = 0; it < 16; ++it) {
        int f = it * 256 + t;     // float4 index within 64x256 panel
        int r = f >> 6;           // row (wave-uniform)
        int q = f & 63;           // float4 within row (== lane)
        float4 v = reinterpret_cast<const float4*>(src)[f];
        float ss = v.x * v.x + v.y * v.y + v.z * v.z + v.w * v.w;
        ushort4 pk;
        pk.x = f2bf(v.x); pk.y = f2bf(v.y); pk.z = f2bf(v.z); pk.w = f2bf(v.w);
        int c = q >> 1, h = q & 1;   // 16B chunk index, half within chunk
        int off = r * 512 + (((c ^ (r & 7)) << 4) | (h << 3));
        *reinterpret_cast<ushort4*>(reinterpret_cast<char*>(panel) + off) = pk;
        #pragma unroll
        for (int o = 32; o > 0; o >>= 1) ss += __shfl_xor(ss, o);
        if (lane == 0) nrm[r] = ss;
    }
}

// One block = one 64x64 lower-triangular supertile; 4 waves = 2x2 quadrants of 32x32.
__global__ __launch_bounds__(256) void dist_fused(const float* __restrict__ x,
                                                  float* __restrict__ out) {
    __shared__ unsigned short pa[STRIP * DD];   // 32 KB
    __shared__ unsigned short pb[STRIP * DD];   // 32 KB
    __shared__ float na[STRIP];
    __shared__ float nb[STRIP];

    int t    = threadIdx.x;
    int lane = t & 63;
    int w    = t >> 6;

    int bid = blockIdx.x;
    int b   = bid / SUPER_PER_B;
    int s   = bid - b * SUPER_PER_B;
    int ti = (int)((sqrtf(8.0f * (float)s + 1.0f) - 1.0f) * 0.5f);
    while ((ti + 1) * (ti + 2) / 2 <= s) ti++;
    while (ti * (ti + 1) / 2 > s) ti--;
    int tj = s - ti * (ti + 1) / 2;             // tj <= ti

    const float* xa = x + (size_t)(b * SS + ti * STRIP) * DD;
    stage_panel(xa, pa, na, t, lane);
    if (ti != tj) {
        const float* xbp = x + (size_t)(b * SS + tj * STRIP) * DD;
        stage_panel(xbp, pb, nb, t, lane);
    }
    __syncthreads();

    const unsigned short* PB = (ti == tj) ? pa : pb;
    const float* NB          = (ti == tj) ? na : nb;

    int wr  = w >> 1, wc = w & 1;               // wave's 32x32 quadrant
    int r16 = lane & 15;                        // operand row within 16-tile; C/D col
    int kq  = lane >> 4;                        // operand k-quad; C/D row-quad
    int la0 = wr * 32 + r16, la1 = la0 + 16;
    int lb0 = wc * 32 + r16, lb1 = lb0 + 16;

    const char* cpa = reinterpret_cast<const char*>(pa);
    const char* cpb = reinterpret_cast<const char*>(PB);

    f32x4 acc00 = {0.f,0.f,0.f,0.f}, acc01 = {0.f,0.f,0.f,0.f};
    f32x4 acc10 = {0.f,0.f,0.f,0.f}, acc11 = {0.f,0.f,0.f,0.f};

    #pragma unroll
    for (int stp = 0; stp < 8; ++stp) {
        int c0 = kq + 4 * stp;                  // 16B chunk = elements [stp*32+kq*8, +8)
        bf16x8 a0 = *reinterpret_cast<const bf16x8*>(cpa + la0 * 512 + ((c0 ^ (la0 & 7)) << 4));
        bf16x8 a1 = *reinterpret_cast<const bf16x8*>(cpa + la1 * 512 + ((c0 ^ (la1 & 7)) << 4));
        bf16x8 b0 = *reinterpret_cast<const bf16x8*>(cpb + lb0 * 512 + ((c0 ^ (lb0 & 7)) << 4));
        bf16x8 b1 = *reinterpret_cast<const bf16x8*>(cpb + lb1 * 512 + ((c0 ^ (lb1 & 7)) << 4));
        acc00 = __builtin_amdgcn_mfma_f32_16x16x32_bf16(a0, b0, acc00, 0, 0, 0);
        acc01 = __builtin_amdgcn_mfma_f32_16x16x32_bf16(a0, b1, acc01, 0, 0, 0);
        acc10 = __builtin_amdgcn_mfma_f32_16x16x32_bf16(a1, b0, acc10, 0, 0, 0);
        acc11 = __builtin_amdgcn_mfma_f32_16x16x32_bf16(a1, b1, acc11, 0, 0, 0);
    }

    // C/D layout (m89-verified): col = lane&15 -> j, row = kq*4 + reg -> i
    float* outb = out + (size_t)b * PP;
    #pragma unroll
    for (int q = 0; q < 2; ++q) {
        int jgl = wc * 32 + q * 16 + r16;
        int jg  = tj * STRIP + jgl;
        float nj = NB[jgl];
        #pragma unroll
        for (int p = 0; p < 2; ++p) {
            f32x4 a;
            if (q == 0) a = (p == 0) ? acc00 : acc10;
            else        a = (p == 0) ? acc01 : acc11;
            #pragma unroll
            for (int r = 0; r < 4; ++r) {
                int igl = wr * 32 + p * 16 + kq * 4 + r;
                int ig  = ti * STRIP + igl;
                if (ig > jg) {
                    float ni = na[igl];
                    float d2 = ni + nj - 2.0f * a[r];
                    d2 = fmaxf(d2, 1e-7f);
                    outb[(size_t)(ig * (ig - 1) / 2) + jg] = sqrtf(d2);
                }
            }
        }
    }
}

extern "C" void kernel_launch(void* const* d_in, const int* in_sizes, int n_in,
                              void* d_out, int out_size, void* d_ws, size_t ws_size,
                              hipStream_t stream) {
    const float* x = (const float*)d_in[0];
    float* out = (float*)d_out;
    (void)d_ws; (void)ws_size;                   // single fused kernel, no workspace
    dist_fused<<<NBLOCKS, 256, 0, stream>>>(x, out);
}

// Round 4
// 68.724 us; speedup vs baseline: 1.0705x; 1.0705x over previous
//
#include <hip/hip_runtime.h>
#include <hip/hip_bf16.h>
#include <math.h>

#define BB 8
#define SS 512
#define DD 256
#define PP (SS * (SS - 1) / 2)   // 130816 pairs per batch
#define TILES_PER_B (32 * 33 / 2) // 528 triangular 16x16 tiles

typedef short bf16x8 __attribute__((ext_vector_type(8)));
typedef float f32x4 __attribute__((ext_vector_type(4)));

// fp32 -> bf16 round-to-nearest-even (inputs are finite gaussians, no NaN path needed)
static __device__ inline unsigned short f2bf(float f) {
    unsigned int u = __float_as_uint(f);
    unsigned int r = u + 0x7fffu + ((u >> 16) & 1u);
    return (unsigned short)(r >> 16);
}

// One wave per row: convert 256 fp32 -> bf16, compute fp32 sum of squares.
// 4096 waves of pure TLP hide the cold-HBM read latency (this is why the
// two-kernel structure beats both fused variants — measured R1/R3 vs R0/R2).
__global__ __launch_bounds__(256) void prep_kernel(const float* __restrict__ x,
                                                   unsigned short* __restrict__ xb,
                                                   float* __restrict__ norms) {
    int row  = blockIdx.x * 4 + (threadIdx.x >> 6); // 4096 rows total
    int lane = threadIdx.x & 63;
    const float4* src = reinterpret_cast<const float4*>(x + (size_t)row * DD) + lane;
    float4 v = *src;
    float ss = v.x * v.x + v.y * v.y + v.z * v.z + v.w * v.w;
    ushort4 pk;
    pk.x = f2bf(v.x); pk.y = f2bf(v.y); pk.z = f2bf(v.z); pk.w = f2bf(v.w);
    *reinterpret_cast<ushort4*>(xb + (size_t)row * DD + lane * 4) = pk;
    #pragma unroll
    for (int o = 32; o > 0; o >>= 1) ss += __shfl_down(ss, o);
    if (lane == 0) norms[row] = ss;
}

// One wave per 16x16 tile of the lower-triangular pair matrix.
// Gram via mfma_f32_16x16x32_bf16; epilogue d = sqrt(max(ni+nj-2g, eps)).
__global__ __launch_bounds__(256) void dist_kernel(const unsigned short* __restrict__ xb,
                                                   const float* __restrict__ norms,
                                                   float* __restrict__ out) {
    int w    = blockIdx.x * 4 + (threadIdx.x >> 6); // 0..4223
    int lane = threadIdx.x & 63;
    int b    = w / TILES_PER_B;
    int tidx = w - b * TILES_PER_B;
    // largest ti with ti*(ti+1)/2 <= tidx
    int ti = (int)((sqrtf(8.0f * (float)tidx + 1.0f) - 1.0f) * 0.5f);
    while ((ti + 1) * (ti + 2) / 2 <= tidx) ti++;
    while (ti * (ti + 1) / 2 > tidx) ti--;
    int tj = tidx - ti * (ti + 1) / 2;

    int nidx = lane & 15;  // m for A-rows, n for B-rows (both use lane&15)
    int quad = lane >> 4;  // k-quad for operands; row-quad for C/D

    const unsigned short* arow = xb + ((size_t)(b * SS + ti * 16 + nidx)) * DD + quad * 8;
    const unsigned short* brow = xb + ((size_t)(b * SS + tj * 16 + nidx)) * DD + quad * 8;

    f32x4 acc = {0.f, 0.f, 0.f, 0.f};
    #pragma unroll
    for (int k = 0; k < DD; k += 32) {
        bf16x8 av = *reinterpret_cast<const bf16x8*>(arow + k);
        bf16x8 bv = *reinterpret_cast<const bf16x8*>(brow + k);
        acc = __builtin_amdgcn_mfma_f32_16x16x32_bf16(av, bv, acc, 0, 0, 0);
    }

    // C/D layout (m89-verified): col = lane&15 -> j index, row = quad*4+reg -> i index
    int jg = tj * 16 + nidx;
    float nj = norms[b * SS + jg];
    float* outb = out + (size_t)b * PP;
    #pragma unroll
    for (int r = 0; r < 4; r++) {
        int ig = ti * 16 + quad * 4 + r;
        if (ig > jg) {
            float ni = norms[b * SS + ig];
            float d2 = ni + nj - 2.0f * acc[r];
            d2 = fmaxf(d2, 1e-7f);
            outb[(size_t)(ig * (ig - 1) / 2) + jg] = sqrtf(d2);
        }
    }
}

extern "C" void kernel_launch(void* const* d_in, const int* in_sizes, int n_in,
                              void* d_out, int out_size, void* d_ws, size_t ws_size,
                              hipStream_t stream) {
    const float* x = (const float*)d_in[0];
    float* out = (float*)d_out;
    unsigned short* xb = (unsigned short*)d_ws;                      // 2 MB bf16 copy
    float* norms = (float*)((char*)d_ws + (size_t)BB * SS * DD * 2); // 16 KB norms

    prep_kernel<<<1024, 256, 0, stream>>>(x, xb, norms);
    dist_kernel<<<1056, 256, 0, stream>>>(xb, norms, out);
}